// Round 1
// baseline (3799.967 us; speedup 1.0000x reference)
//
#include <hip/hip_runtime.h>
#include <hip/hip_bf16.h>

typedef __hip_bfloat16 bf16;

#define BATCH 1024

// ---------------- workspace layout (float offsets) ----------------
#define OFF_A1 0
#define OFF_C1 64
#define OFF_A2 128
#define OFF_C2 160
#define OFF_A3 192
#define OFF_C3 224
#define OFF_LP 256
#define OFF_P1S 512
#define OFF_P1Q (OFF_P1S + 64*1024)
#define OFF_P2S (OFF_P1Q + 64*1024)
#define OFF_P2Q (OFF_P2S + 32*4096)
#define OFF_P3S (OFF_P2Q + 32*4096)
#define OFF_P3Q (OFF_P3S + 32*4096)
#define FLT_END (OFF_P3Q + 32*4096)          // 655872 floats

#define X1_BYTE ((size_t)FLT_END * 4)        // bf16 x1 raw (B,34,7,64)
#define X1_N    (15597568u)
#define X2_BYTE (X1_BYTE + (size_t)X1_N * 2) // bf16 x2 raw (B,36,27,32)
#define X2_N    (31850496u)
#define X3_BYTE (X2_BYTE + (size_t)X2_N * 2) // bf16 x3 raw (B,36,55,32)
#define X3_N    (64880640u)
#define O4_BYTE (X3_BYTE + (size_t)X3_N * 2) // f32 out4 (B,3780)

// ---------------- d_out layout (float offsets) ----------------
#define OUT0 0         // X[:,:,1:]        (B,30,5)
#define OUT1 153600    // edge_index       (2,870)
#define OUT2 155340    // edge_attr[:,:,1:](B,870,3)
#define OUT3 2827980   // 1-X[:,:,0]       (B,30)
#define OUT4 2858700   // 1-ea[:,:,0]      (B,870)
#define OUT5 3749580   // batch            (B*30)
#define OUT6 3780300   // X_hard[:,:,1:]   (B,30,5)
#define OUT7 3933900   // ea_hard[:,:,1:]  (B,870,3)
#define OUT8 6606540   // 1-X_hard[:,:,0]  (B,30)
#define OUT9 6637260   // 1-ea_hard[:,:,0] (B,870)
#define OUT10 7528140  // log_prob scalar

__device__ __forceinline__ float b2f(bf16 v){ return __bfloat162float(v); }
__device__ __forceinline__ bf16 f2b(float v){ return __float2bfloat16(v); }

// ============ deconv1: Z(B,32) -> x1 raw (B,34,7,64), per-channel partial stats ============
__global__ __launch_bounds__(256) void k_dc1(const float* __restrict__ Z, const float* __restrict__ W1,
                                             bf16* __restrict__ x1, float* __restrict__ ws){
  const int b = blockIdx.x, t = threadIdx.x;
  __shared__ float zs[32];
  __shared__ float w1s[3*7*64];
  __shared__ float red[256];
  if (t < 32) zs[t] = Z[b*32 + t];
  for (int i = t; i < 1344; i += 256) w1s[i] = W1[i];
  __syncthreads();
  float lsum = 0.f, lsq = 0.f;
  for (int idx = t; idx < 15232; idx += 256){
    int co = idx & 63;
    int wo = (idx >> 6) % 7;
    int ho = idx / 448;
    int kw = 6 - wo;                       // only W-tap hitting the single input column
    float y = 0.f;
    #pragma unroll
    for (int kh = 0; kh < 3; ++kh){
      int hi = ho + kh - 2;                // lhs-pad = k-1-p = 2
      if (hi >= 0 && hi < 32) y += zs[hi] * w1s[(kh*7 + kw)*64 + co];
    }
    x1[(size_t)b*15232 + idx] = f2b(y);
    lsum += y; lsq += y*y;
  }
  red[t] = lsum; __syncthreads();
  if (t < 64) ws[OFF_P1S + t*1024 + b] = red[t] + red[t+64] + red[t+128] + red[t+192];
  __syncthreads();
  red[t] = lsq; __syncthreads();
  if (t < 64) ws[OFF_P1Q + t*1024 + b] = red[t] + red[t+64] + red[t+128] + red[t+192];
}

// ============ BN finalize: reduce partials -> a = g*rsqrt(var+eps), c = b - a*mean ============
__global__ __launch_bounds__(256) void k_fin(float* __restrict__ ws, const float* __restrict__ g,
                                             const float* __restrict__ bb, int ps, int pq, int npart,
                                             float inv_n, int ao, int co, int zlp){
  const int c = blockIdx.x, t = threadIdx.x;
  __shared__ float r1[256], r2[256];
  float s = 0.f, q = 0.f;
  for (int i = t; i < npart; i += 256){ s += ws[ps + c*npart + i]; q += ws[pq + c*npart + i]; }
  r1[t] = s; r2[t] = q; __syncthreads();
  for (int off = 128; off > 0; off >>= 1){
    if (t < off){ r1[t] += r1[t+off]; r2[t] += r2[t+off]; }
    __syncthreads();
  }
  if (t == 0){
    float m  = r1[0] * inv_n;
    float v  = r2[0] * inv_n - m*m;
    float is = rsqrtf(v + 1e-5f);
    float a  = g[c] * is;
    ws[ao + c] = a;
    ws[co + c] = bb[c] - a*m;
  }
  if (zlp && c == 0 && t == 0) ws[OFF_LP] = 0.f;
}

// ============ deconv2: act1(BN+ReLU of x1) -> x2 raw (B,36,27,32), s=(1,4), pad lo=(2,2) ============
__global__ __launch_bounds__(256) void k_dc2(const bf16* __restrict__ x1, const float* __restrict__ W2g,
                                             bf16* __restrict__ x2, float* __restrict__ ws){
  const int b = blockIdx.x, t = threadIdx.x;
  const int ho0 = blockIdx.y * 9, coh = blockIdx.z * 16;
  __shared__ float acts[11*448];       // rows ho0-2 .. ho0+8, (wi,ci) = 7*64
  __shared__ float w2s[9*16*68];       // [tap][col][ci pad 68]
  __shared__ float a1s[64], c1s[64], red[256];
  if (t < 64){ a1s[t] = ws[OFF_A1 + t]; c1s[t] = ws[OFF_C1 + t]; }
  __syncthreads();
  for (int i = t; i < 11*448; i += 256){
    int r = i / 448, rem = i % 448, c = i & 63;
    int hi = ho0 - 2 + r;
    float v = 0.f;
    if (hi >= 0 && hi < 34){
      float x = b2f(x1[((size_t)b*34 + hi)*448 + rem]);
      v = fmaxf(a1s[c]*x + c1s[c], 0.f);
    }
    acts[i] = v;
  }
  for (int i = t; i < 9*16*64; i += 256){
    int ci = i & 63, col = (i >> 6) & 15, tap = i >> 10;
    w2s[(tap*16 + col)*68 + ci] = W2g[(tap*64 + ci)*32 + coh + col];
  }
  __syncthreads();
  float lsum = 0.f, lsq = 0.f;
  for (int idx = t; idx < 9*27*16; idx += 256){
    int col = idx & 15, wo = (idx >> 4) % 27, hrel = idx / 432;
    float y = 0.f;
    #pragma unroll
    for (int kh = 0; kh < 3; ++kh){
      int rrel = hrel + kh;
      #pragma unroll
      for (int kw = 0; kw < 3; ++kw){
        int wd = wo + kw - 2;
        if (wd >= 0 && wd < 25 && (wd & 3) == 0){
          const float4* ap = (const float4*)&acts[(rrel*7 + (wd >> 2))*64];
          const float4* wp = (const float4*)&w2s[((kh*3 + kw)*16 + col)*68];
          #pragma unroll
          for (int qq = 0; qq < 16; ++qq){
            float4 fa = ap[qq], fw = wp[qq];
            y += fa.x*fw.x + fa.y*fw.y + fa.z*fw.z + fa.w*fw.w;
          }
        }
      }
    }
    int ho = ho0 + hrel;
    x2[(((size_t)b*36 + ho)*27 + wo)*32 + coh + col] = f2b(y);
    lsum += y; lsq += y*y;
  }
  red[t] = lsum; __syncthreads();
  if (t < 16){ float s = 0.f; for (int g2 = 0; g2 < 16; ++g2) s += red[t + 16*g2];
               ws[OFF_P2S + (coh + t)*4096 + (b*4 + blockIdx.y)] = s; }
  __syncthreads();
  red[t] = lsq; __syncthreads();
  if (t < 16){ float s = 0.f; for (int g2 = 0; g2 < 16; ++g2) s += red[t + 16*g2];
               ws[OFF_P2Q + (coh + t)*4096 + (b*4 + blockIdx.y)] = s; }
}

// ============ deconv3: act2 -> x3 raw (B,36,55,32), s=(1,2), pad lo=(1,2) ============
__global__ __launch_bounds__(256) void k_dc3(const bf16* __restrict__ x2, const float* __restrict__ W3g,
                                             bf16* __restrict__ x3, float* __restrict__ ws){
  const int b = blockIdx.x, t = threadIdx.x;
  const int ho0 = blockIdx.y * 9, coh = blockIdx.z * 16;
  __shared__ float acts[11*864];       // rows ho0-1 .. ho0+9, (wi,ci) = 27*32
  __shared__ float w3s[9*16*36];       // [tap][col][ci pad 36]
  __shared__ float a2s[32], c2s[32], red[256];
  if (t < 32){ a2s[t] = ws[OFF_A2 + t]; c2s[t] = ws[OFF_C2 + t]; }
  __syncthreads();
  for (int i = t; i < 11*864; i += 256){
    int r = i / 864, rem = i % 864, c = i & 31;
    int hi = ho0 - 1 + r;
    float v = 0.f;
    if (hi >= 0 && hi < 36){
      float x = b2f(x2[((size_t)b*36 + hi)*864 + rem]);
      v = fmaxf(a2s[c]*x + c2s[c], 0.f);
    }
    acts[i] = v;
  }
  for (int i = t; i < 9*16*32; i += 256){
    int ci = i & 31, col = (i >> 5) & 15, tap = i >> 9;
    w3s[(tap*16 + col)*36 + ci] = W3g[(tap*32 + ci)*32 + coh + col];
  }
  __syncthreads();
  float lsum = 0.f, lsq = 0.f;
  for (int idx = t; idx < 9*55*16; idx += 256){
    int col = idx & 15, wo = (idx >> 4) % 55, hrel = idx / 880;
    float y = 0.f;
    #pragma unroll
    for (int kh = 0; kh < 3; ++kh){
      int rrel = hrel + kh;
      #pragma unroll
      for (int kw = 0; kw < 3; ++kw){
        int wd = wo + kw - 2;
        if (wd >= 0 && wd < 53 && (wd & 1) == 0){
          const float4* ap = (const float4*)&acts[(rrel*27 + (wd >> 1))*32];
          const float4* wp = (const float4*)&w3s[((kh*3 + kw)*16 + col)*36];
          #pragma unroll
          for (int qq = 0; qq < 8; ++qq){
            float4 fa = ap[qq], fw = wp[qq];
            y += fa.x*fw.x + fa.y*fw.y + fa.z*fw.z + fa.w*fw.w;
          }
        }
      }
    }
    int ho = ho0 + hrel;
    x3[(((size_t)b*36 + ho)*55 + wo)*32 + coh + col] = f2b(y);
    lsum += y; lsq += y*y;
  }
  red[t] = lsum; __syncthreads();
  if (t < 16){ float s = 0.f; for (int g2 = 0; g2 < 16; ++g2) s += red[t + 16*g2];
               ws[OFF_P3S + (coh + t)*4096 + (b*4 + blockIdx.y)] = s; }
  __syncthreads();
  red[t] = lsq; __syncthreads();
  if (t < 16){ float s = 0.f; for (int g2 = 0; g2 < 16; ++g2) s += red[t + 16*g2];
               ws[OFF_P3Q + (coh + t)*4096 + (b*4 + blockIdx.y)] = s; }
}

// ============ deconv4: act3 -> out4 (B,36,105), s=(1,2), pad lo=(1,0), C_out=1 ============
__global__ __launch_bounds__(256) void k_dc4(const bf16* __restrict__ x3, const float* __restrict__ W4g,
                                             float* __restrict__ out4, float* __restrict__ ws){
  const int b = blockIdx.x, t = threadIdx.x;
  const int ho0 = blockIdx.y * 4;
  __shared__ float acts[6*1760];       // rows ho0-1 .. ho0+4, (wi,ci) = 55*32
  __shared__ float w4s[480];
  __shared__ float a3s[32], c3s[32];
  if (t < 32){ a3s[t] = ws[OFF_A3 + t]; c3s[t] = ws[OFF_C3 + t]; }
  __syncthreads();
  for (int i = t; i < 6*1760; i += 256){
    int r = i / 1760, rem = i % 1760, c = i & 31;
    int hi = ho0 - 1 + r;
    float v = 0.f;
    if (hi >= 0 && hi < 36){
      float x = b2f(x3[((size_t)b*36 + hi)*1760 + rem]);
      v = fmaxf(a3s[c]*x + c3s[c], 0.f);
    }
    acts[i] = v;
  }
  for (int i = t; i < 480; i += 256) w4s[i] = W4g[i];
  __syncthreads();
  for (int idx = t; idx < 4*105; idx += 256){
    int wo = idx % 105, hrel = idx / 105;
    float y = 0.f;
    #pragma unroll
    for (int kh = 0; kh < 3; ++kh){
      int rrel = hrel + kh;
      #pragma unroll
      for (int kw = 0; kw < 5; ++kw){
        int wd = wo + kw;                       // pad lo = 0
        if ((wd & 1) == 0 && wd < 109){
          const float4* ap = (const float4*)&acts[(rrel*55 + (wd >> 1))*32];
          const float4* wp = (const float4*)&w4s[(kh*5 + kw)*32];
          #pragma unroll
          for (int qq = 0; qq < 8; ++qq){
            float4 fa = ap[qq], fw = wp[qq];
            y += fa.x*fw.x + fa.y*fw.y + fa.z*fw.z + fa.w*fw.w;
          }
        }
      }
    }
    int ho = ho0 + hrel;
    out4[((size_t)b*36 + ho)*105 + wo] = y;
  }
}

// ============ node softmax / one-hot / outputs 0,3,5,6,8 + log_prob partial ============
__global__ __launch_bounds__(256) void k_node(const float* __restrict__ o4, float* __restrict__ dout,
                                              float* __restrict__ ws){
  const int t = threadIdx.x;
  const int tg = blockIdx.x*256 + t;    // < 30720
  __shared__ float red[256];
  float lp = 0.f;
  {
    int b = tg / 30, n = tg - b*30;
    const float* p = o4 + (size_t)b*3780 + n*126;
    float l[6]; float mx = -1e30f;
    #pragma unroll
    for (int j = 0; j < 6; ++j){ l[j] = p[j]; mx = fmaxf(mx, l[j]); }
    float e[6]; float s = 0.f;
    #pragma unroll
    for (int j = 0; j < 6; ++j){ e[j] = expf(l[j] - mx); s += e[j]; }
    float inv = 1.f / s;
    int am = 0; float best = e[0];
    #pragma unroll
    for (int j = 1; j < 6; ++j){ if (e[j] > best){ best = e[j]; am = j; } }
    #pragma unroll
    for (int j = 0; j < 5; ++j) dout[OUT0 + (size_t)tg*5 + j] = e[j+1]*inv;
    dout[OUT3 + tg] = 1.f - e[0]*inv;
    #pragma unroll
    for (int j = 0; j < 5; ++j) dout[OUT6 + (size_t)tg*5 + j] = (am == j+1) ? 1.f : 0.f;
    dout[OUT8 + tg] = (am != 0) ? 1.f : 0.f;
    dout[OUT5 + tg] = (float)b;
    lp = logf(best*inv + 1e-7f);
  }
  red[t] = lp; __syncthreads();
  for (int off = 128; off > 0; off >>= 1){ if (t < off) red[t] += red[t+off]; __syncthreads(); }
  if (t == 0) atomicAdd(&ws[OFF_LP], red[0]);
}

// ============ edge softmax / one-hot / outputs 1,2,4,7,9 + log_prob partial ============
__global__ __launch_bounds__(256) void k_edge(const float* __restrict__ o4, float* __restrict__ dout,
                                              float* __restrict__ ws){
  const int t = threadIdx.x;
  const int tg = blockIdx.x*256 + t;    // < 445440 = 1024*435
  __shared__ float red[256];
  float lp = 0.f;
  {
    int b = tg / 435, k = tg - b*435;
    int i = 0, rem = k;
    while (rem >= 29 - i){ rem -= 29 - i; ++i; }   // triu_indices(30,1) row-major
    int j = i + 1 + rem;
    const float* p = o4 + (size_t)b*3780 + i*126 + 6 + j*4;
    float l0 = p[0], l1 = p[1], l2 = p[2], l3 = p[3];
    float mx = fmaxf(fmaxf(l0, l1), fmaxf(l2, l3));
    float e0 = expf(l0-mx), e1 = expf(l1-mx), e2 = expf(l2-mx), e3 = expf(l3-mx);
    float inv = 1.f / (e0 + e1 + e2 + e3);
    float pr0 = e0*inv, pr1 = e1*inv, pr2 = e2*inv, pr3 = e3*inv;
    int am = 0; float best = pr0;
    if (pr1 > best){ best = pr1; am = 1; }
    if (pr2 > best){ best = pr2; am = 2; }
    if (pr3 > best){ best = pr3; am = 3; }
    size_t e1i = (size_t)b*870 + k, e2i = e1i + 435;
    dout[OUT2 + e1i*3 + 0] = pr1; dout[OUT2 + e1i*3 + 1] = pr2; dout[OUT2 + e1i*3 + 2] = pr3;
    dout[OUT2 + e2i*3 + 0] = pr1; dout[OUT2 + e2i*3 + 1] = pr2; dout[OUT2 + e2i*3 + 2] = pr3;
    dout[OUT4 + e1i] = 1.f - pr0;  dout[OUT4 + e2i] = 1.f - pr0;
    float h1 = (am == 1) ? 1.f : 0.f, h2 = (am == 2) ? 1.f : 0.f, h3 = (am == 3) ? 1.f : 0.f;
    dout[OUT7 + e1i*3 + 0] = h1; dout[OUT7 + e1i*3 + 1] = h2; dout[OUT7 + e1i*3 + 2] = h3;
    dout[OUT7 + e2i*3 + 0] = h1; dout[OUT7 + e2i*3 + 1] = h2; dout[OUT7 + e2i*3 + 2] = h3;
    dout[OUT9 + e1i] = (am != 0) ? 1.f : 0.f;  dout[OUT9 + e2i] = (am != 0) ? 1.f : 0.f;
    if (b == 0){
      dout[OUT1 + k]        = (float)i;
      dout[OUT1 + 435 + k]  = (float)j;
      dout[OUT1 + 870 + k]  = (float)j;
      dout[OUT1 + 1305 + k] = (float)i;
    }
    lp = logf(best + 1e-7f);
  }
  red[t] = lp; __syncthreads();
  for (int off = 128; off > 0; off >>= 1){ if (t < off) red[t] += red[t+off]; __syncthreads(); }
  if (t == 0) atomicAdd(&ws[OFF_LP], red[0]);
}

__global__ void k_lp_copy(float* __restrict__ dout, const float* __restrict__ ws){
  if (threadIdx.x == 0 && blockIdx.x == 0) dout[OUT10] = ws[OFF_LP];
}

extern "C" void kernel_launch(void* const* d_in, const int* in_sizes, int n_in,
                              void* d_out, int out_size, void* d_ws, size_t ws_size,
                              hipStream_t stream) {
  const float* Z  = (const float*)d_in[0];
  const float* W1 = (const float*)d_in[1];
  const float* W2 = (const float*)d_in[2];
  const float* W3 = (const float*)d_in[3];
  const float* W4 = (const float*)d_in[4];
  const float* g1 = (const float*)d_in[5];
  const float* b1 = (const float*)d_in[6];
  const float* g2 = (const float*)d_in[7];
  const float* b2 = (const float*)d_in[8];
  const float* g3 = (const float*)d_in[9];
  const float* b3 = (const float*)d_in[10];

  float* ws  = (float*)d_ws;
  char*  wsb = (char*)d_ws;
  bf16*  x1  = (bf16*)(wsb + X1_BYTE);
  bf16*  x2  = (bf16*)(wsb + X2_BYTE);
  bf16*  x3  = (bf16*)(wsb + X3_BYTE);
  float* o4  = (float*)(wsb + O4_BYTE);
  float* dout = (float*)d_out;

  k_dc1<<<dim3(1024), dim3(256), 0, stream>>>(Z, W1, x1, ws);
  k_fin<<<dim3(64), dim3(256), 0, stream>>>(ws, g1, b1, OFF_P1S, OFF_P1Q, 1024,
                                            1.f/243712.f, OFF_A1, OFF_C1, 0);
  k_dc2<<<dim3(1024, 4, 2), dim3(256), 0, stream>>>(x1, W2, x2, ws);
  k_fin<<<dim3(32), dim3(256), 0, stream>>>(ws, g2, b2, OFF_P2S, OFF_P2Q, 4096,
                                            1.f/995328.f, OFF_A2, OFF_C2, 0);
  k_dc3<<<dim3(1024, 4, 2), dim3(256), 0, stream>>>(x2, W3, x3, ws);
  k_fin<<<dim3(32), dim3(256), 0, stream>>>(ws, g3, b3, OFF_P3S, OFF_P3Q, 4096,
                                            1.f/2027520.f, OFF_A3, OFF_C3, 1);
  k_dc4<<<dim3(1024, 9), dim3(256), 0, stream>>>(x3, W4, o4, ws);
  k_node<<<dim3(120), dim3(256), 0, stream>>>(o4, dout, ws);
  k_edge<<<dim3(1740), dim3(256), 0, stream>>>(o4, dout, ws);
  k_lp_copy<<<dim3(1), dim3(64), 0, stream>>>(dout, ws);
}

// Round 2
// 871.390 us; speedup vs baseline: 4.3608x; 4.3608x over previous
//
#include <hip/hip_runtime.h>
#include <hip/hip_bf16.h>

typedef __hip_bfloat16 bf16;
typedef __attribute__((ext_vector_type(8))) short short8;
typedef __attribute__((ext_vector_type(4))) float floatx4;
typedef __bf16 bf16x8 __attribute__((ext_vector_type(8)));

// ---------------- workspace layout ----------------
// float offsets
#define OFF_A1 0
#define OFF_C1 64
#define OFF_A2 128
#define OFF_C2 160
#define OFF_A3 192
#define OFF_C3 224
#define OFF_LP 256
#define OFF_P1S 512
#define OFF_P1Q 66048            // P1S + 64*1024
#define OFF_P2S 131584           // P1Q + 64*1024
#define OFF_P2Q 205312           // P2S + 32*2304
#define OFF_P3S 279040           // P2Q + 32*2304
#define OFF_P3Q 426496           // P3S + 32*4608
#define FLT_END 573952           // P3Q + 32*4608

// byte offsets
#define FW2_BYTE 2295808u        // FLT_END*4
#define FW3_BYTE 2332672u        // +18432 shorts *2
#define X1_BYTE  2351104u        // +9216*2
#define X2_BYTE  33546240u       // + (34*7*1024*64)*2
#define X3_BYTE  97247232u       // + (36*27*1024*32)*2
#define O4_BYTE  227008512u      // + (36*55*1024*32)*2

// ---------------- d_out layout (float offsets) ----------------
#define OUT0 0
#define OUT1 153600
#define OUT2 155340
#define OUT3 2827980
#define OUT4 2858700
#define OUT5 3749580
#define OUT6 3780300
#define OUT7 3933900
#define OUT8 6606540
#define OUT9 6637260
#define OUT10 7528140

__device__ __forceinline__ float b2f(bf16 v){ return __bfloat162float(v); }
__device__ __forceinline__ bf16 f2b(float v){ return __float2bfloat16(v); }
__device__ __forceinline__ unsigned short f2bu(float v){ bf16 h = __float2bfloat16(v); return *(unsigned short*)&h; }

__device__ __forceinline__ floatx4 mfma16(short8 a, short8 b, floatx4 c){
  return __builtin_amdgcn_mfma_f32_16x16x32_bf16(__builtin_bit_cast(bf16x8, a),
                                                 __builtin_bit_cast(bf16x8, b), c, 0, 0, 0);
}

// normalize 2 bf16 packed in a uint (BN scale/shift + ReLU), repack to bf16
__device__ __forceinline__ unsigned int nrm2(unsigned int u, float a0, float c0, float a1, float c1){
  float x0 = __uint_as_float(u << 16);
  float x1 = __uint_as_float(u & 0xffff0000u);
  float y0 = fmaxf(fmaf(a0, x0, c0), 0.f);
  float y1 = fmaxf(fmaf(a1, x1, c1), 0.f);
  return (unsigned int)f2bu(y0) | ((unsigned int)f2bu(y1) << 16);
}

// ============ weight fragment prep: A[m=co][k=ci] per tap, bf16 frag layout ============
__global__ __launch_bounds__(256) void k_prep(const float* __restrict__ W2, const float* __restrict__ W3,
                                              unsigned short* __restrict__ fw2, unsigned short* __restrict__ fw3){
  const int t = blockIdx.x*256 + threadIdx.x;
  if (t < 2304){   // fw2: [tap9][mt2][kc2][L64][8]
    const int L = t & 63, kc = (t>>6)&1, mt = (t>>7)&1, tap = t>>8;
    const int co = mt*16 + (L&15), ci0 = kc*32 + ((L>>4)&3)*8;
    #pragma unroll
    for (int j = 0; j < 8; ++j)
      fw2[(size_t)t*8 + j] = f2bu(W2[((size_t)tap*64 + ci0 + j)*32 + co]);
  }
  if (t < 1152){   // fw3: [tap9][mt2][L64][8]
    const int L = t & 63, mt = (t>>6)&1, tap = t>>7;
    const int co = mt*16 + (L&15), ci0 = ((L>>4)&3)*8;
    #pragma unroll
    for (int j = 0; j < 8; ++j)
      fw3[(size_t)t*8 + j] = f2bu(W3[((size_t)tap*32 + ci0 + j)*32 + co]);
  }
}

// ============ deconv1: Z(B,32) -> x1 raw pixel-major (34,7,1024,64) + partial stats ============
__global__ __launch_bounds__(256) void k_dc1(const float* __restrict__ Z, const float* __restrict__ W1,
                                             bf16* __restrict__ x1, float* __restrict__ ws){
  const int b = blockIdx.x, t = threadIdx.x;
  __shared__ float zs[32];
  __shared__ float w1s[3*7*64];
  __shared__ float red[256];
  if (t < 32) zs[t] = Z[b*32 + t];
  for (int i = t; i < 1344; i += 256) w1s[i] = W1[i];
  __syncthreads();
  float lsum = 0.f, lsq = 0.f;
  for (int idx = t; idx < 15232; idx += 256){
    int co = idx & 63;
    int wo = (idx >> 6) % 7;
    int ho = idx / 448;
    int kw = 6 - wo;
    float y = 0.f;
    #pragma unroll
    for (int kh = 0; kh < 3; ++kh){
      int hi = ho + kh - 2;
      if (hi >= 0 && hi < 32) y += zs[hi] * w1s[(kh*7 + kw)*64 + co];
    }
    x1[(size_t)(idx >> 6)*65536 + (size_t)b*64 + co] = f2b(y);
    lsum += y; lsq += y*y;
  }
  red[t] = lsum; __syncthreads();
  if (t < 64) ws[OFF_P1S + t*1024 + b] = red[t] + red[t+64] + red[t+128] + red[t+192];
  __syncthreads();
  red[t] = lsq; __syncthreads();
  if (t < 64) ws[OFF_P1Q + t*1024 + b] = red[t] + red[t+64] + red[t+128] + red[t+192];
}

// ============ BN finalize ============
__global__ __launch_bounds__(256) void k_fin(float* __restrict__ ws, const float* __restrict__ g,
                                             const float* __restrict__ bb, int ps, int pq, int npart,
                                             float inv_n, int ao, int co, int zlp){
  const int c = blockIdx.x, t = threadIdx.x;
  __shared__ float r1[256], r2[256];
  float s = 0.f, q = 0.f;
  for (int i = t; i < npart; i += 256){ s += ws[ps + c*npart + i]; q += ws[pq + c*npart + i]; }
  r1[t] = s; r2[t] = q; __syncthreads();
  for (int off = 128; off > 0; off >>= 1){
    if (t < off){ r1[t] += r1[t+off]; r2[t] += r2[t+off]; }
    __syncthreads();
  }
  if (t == 0){
    float m  = r1[0] * inv_n;
    float v  = r2[0] * inv_n - m*m;
    float is = rsqrtf(v + 1e-5f);
    float a  = g[c] * is;
    ws[ao + c] = a;
    ws[co + c] = bb[c] - a*m;
  }
  if (zlp && c == 0 && t == 0) ws[OFF_LP] = 0.f;
}

// ============ deconv2 (MFMA): x1 (34,7,1024,64) -> x2 raw (36,27,1024,32) + partial stats ============
// relation: hi = ho + kh - 2; wo = 4*wi + 2 - kw
__global__ __launch_bounds__(256) void k2(const unsigned short* __restrict__ x1, const unsigned short* __restrict__ fw2,
                                          unsigned short* __restrict__ x2, float* __restrict__ ws){
  const int t = threadIdx.x;
  const int b0 = blockIdx.x*16, ho = blockIdx.y;
  __shared__ unsigned short sa[21*1024];     // 3 rows x 7 wi, per pixel [kc2][L64][8] bf16
  __shared__ float sa1[64], sc1[64];
  __shared__ float sred[2][4][32];
  if (t < 64){ sa1[t] = ws[OFF_A1+t]; sc1[t] = ws[OFF_C1+t]; }
  __syncthreads();
  for (int c = t; c < 21*128; c += 256){
    const int p = c >> 7, cc = c & 127;
    const int r = p/7, wi = p - r*7;
    const int hi = ho - 2 + r;
    const int L = cc & 63;
    const int ci0 = (cc>>6)*32 + ((L>>4)&3)*8;
    uint4 v = make_uint4(0,0,0,0);
    if (hi >= 0 && hi < 34){
      v = *(const uint4*)(x1 + ((size_t)(hi*7+wi)*1024 + b0 + (L&15))*64 + ci0);
      v.x = nrm2(v.x, sa1[ci0],   sc1[ci0],   sa1[ci0+1], sc1[ci0+1]);
      v.y = nrm2(v.y, sa1[ci0+2], sc1[ci0+2], sa1[ci0+3], sc1[ci0+3]);
      v.z = nrm2(v.z, sa1[ci0+4], sc1[ci0+4], sa1[ci0+5], sc1[ci0+5]);
      v.w = nrm2(v.w, sa1[ci0+6], sc1[ci0+6], sa1[ci0+7], sc1[ci0+7]);
    }
    *(uint4*)((char*)sa + (size_t)p*2048 + cc*16) = v;
  }
  __syncthreads();
  const int w = t>>6, L = t&63;
  floatx4 acc[8][2];
  #pragma unroll
  for (int i = 0; i < 8; ++i){ acc[i][0] = (floatx4)0.f; acc[i][1] = (floatx4)0.f; }
  const int nwi = (w < 3) ? 2 : 1;
  for (int r = 0; r < 3; ++r){
    short8 af[3][2][2];
    #pragma unroll
    for (int kw = 0; kw < 3; ++kw)
      #pragma unroll
      for (int mt = 0; mt < 2; ++mt)
        #pragma unroll
        for (int kc = 0; kc < 2; ++kc)
          af[kw][mt][kc] = *(const short8*)(fw2 + ((((size_t)(r*3+kw)*2 + mt)*2 + kc)*64 + L)*8);
    for (int ii = 0; ii < nwi; ++ii){
      const int wi = 2*w + ii;
      const short8* bp = (const short8*)(sa + (size_t)(r*7 + wi)*1024);
      short8 bf0 = bp[L];
      short8 bf1 = bp[64 + L];
      #pragma unroll
      for (int kw = 0; kw < 3; ++kw){
        const int idx = 4*ii + 2 - kw;
        #pragma unroll
        for (int mt = 0; mt < 2; ++mt){
          acc[idx][mt] = mfma16(af[kw][mt][0], bf0, acc[idx][mt]);
          acc[idx][mt] = mfma16(af[kw][mt][1], bf1, acc[idx][mt]);
        }
      }
    }
  }
  float ss[2][4] = {{0,0,0,0},{0,0,0,0}}, sq[2][4] = {{0,0,0,0},{0,0,0,0}};
  for (int idx = 0; idx < 8; ++idx){
    const int wo = 8*w + idx;
    if (wo >= 27) break;
    #pragma unroll
    for (int mt = 0; mt < 2; ++mt){
      floatx4 a = acc[idx][mt];
      uint2 st;
      st.x = (unsigned int)f2bu(a.x) | ((unsigned int)f2bu(a.y) << 16);
      st.y = (unsigned int)f2bu(a.z) | ((unsigned int)f2bu(a.w) << 16);
      *(uint2*)(x2 + ((size_t)(ho*27+wo)*1024 + b0 + (L&15))*32 + mt*16 + ((L>>4)&3)*4) = st;
      ss[mt][0] += a.x; ss[mt][1] += a.y; ss[mt][2] += a.z; ss[mt][3] += a.w;
      sq[mt][0] += a.x*a.x; sq[mt][1] += a.y*a.y; sq[mt][2] += a.z*a.z; sq[mt][3] += a.w*a.w;
    }
  }
  #pragma unroll
  for (int mt = 0; mt < 2; ++mt)
    #pragma unroll
    for (int r2 = 0; r2 < 4; ++r2){
      float v1 = ss[mt][r2], v2 = sq[mt][r2];
      for (int d = 1; d < 16; d <<= 1){ v1 += __shfl_xor(v1, d, 64); v2 += __shfl_xor(v2, d, 64); }
      if ((L & 15) == 0){
        int cch = mt*16 + ((L>>4)&3)*4 + r2;
        sred[0][w][cch] = v1;
        sred[1][w][cch] = v2;
      }
    }
  __syncthreads();
  if (t < 64){
    const int cch = t & 31, j = t >> 5;
    float tot = sred[j][0][cch] + sred[j][1][cch] + sred[j][2][cch] + sred[j][3][cch];
    const int bid = blockIdx.y*64 + blockIdx.x;
    ws[(j ? OFF_P2Q : OFF_P2S) + cch*2304 + bid] = tot;
  }
}

// ============ deconv3 (MFMA): x2 (36,27,1024,32) -> x3 raw (36,55,1024,32) + partial stats ============
// relation: hi = ho + kh - 1; wo = 2*wi + 2 - kw
__global__ __launch_bounds__(256) void k3(const unsigned short* __restrict__ x2, const unsigned short* __restrict__ fw3,
                                          unsigned short* __restrict__ x3, float* __restrict__ ws){
  const int t = threadIdx.x;
  const int b0 = blockIdx.x*16, ho = blockIdx.y, z = blockIdx.z;
  const int wib = z ? 13 : 0;
  __shared__ unsigned short sa[42*512];      // 3 rows x 14 wi, per pixel [L64][8] bf16
  __shared__ float sa2[32], sc2[32];
  __shared__ float sred[2][4][32];
  if (t < 32){ sa2[t] = ws[OFF_A2+t]; sc2[t] = ws[OFF_C2+t]; }
  __syncthreads();
  for (int c = t; c < 42*64; c += 256){
    const int p = c >> 6, L = c & 63;
    const int r = p/14, wi = wib + (p - r*14);
    const int hi = ho - 1 + r;
    const int ci0 = ((L>>4)&3)*8;
    uint4 v = make_uint4(0,0,0,0);
    if (hi >= 0 && hi < 36){
      v = *(const uint4*)(x2 + ((size_t)(hi*27+wi)*1024 + b0 + (L&15))*32 + ci0);
      v.x = nrm2(v.x, sa2[ci0],   sc2[ci0],   sa2[ci0+1], sc2[ci0+1]);
      v.y = nrm2(v.y, sa2[ci0+2], sc2[ci0+2], sa2[ci0+3], sc2[ci0+3]);
      v.z = nrm2(v.z, sa2[ci0+4], sc2[ci0+4], sa2[ci0+5], sc2[ci0+5]);
      v.w = nrm2(v.w, sa2[ci0+6], sc2[ci0+6], sa2[ci0+7], sc2[ci0+7]);
    }
    *(uint4*)((char*)sa + (size_t)p*1024 + L*16) = v;
  }
  __syncthreads();
  const int w = t>>6, L = t&63;
  const int s0 = z*28 + w*7;
  const int ns = min(7, 55 - s0);
  const int wlo = (s0 >= 2) ? ((s0 - 1) >> 1) : 0;
  const int whi = min(26, (s0 + ns - 1) >> 1);
  floatx4 acc[7][2];
  #pragma unroll
  for (int i = 0; i < 7; ++i){ acc[i][0] = (floatx4)0.f; acc[i][1] = (floatx4)0.f; }
  for (int r = 0; r < 3; ++r){
    short8 af[3][2];
    #pragma unroll
    for (int kw = 0; kw < 3; ++kw)
      #pragma unroll
      for (int mt = 0; mt < 2; ++mt)
        af[kw][mt] = *(const short8*)(fw3 + (((size_t)(r*3+kw)*2 + mt)*64 + L)*8);
    for (int wi = wlo; wi <= whi; ++wi){
      short8 bf = *(const short8*)(sa + (size_t)(r*14 + wi - wib)*512 + L*8);
      #pragma unroll
      for (int kw = 0; kw < 3; ++kw){
        const int wo = 2*wi + 2 - kw;
        if (wo >= s0 && wo < s0 + ns){
          const int idx = wo - s0;
          acc[idx][0] = mfma16(af[kw][0], bf, acc[idx][0]);
          acc[idx][1] = mfma16(af[kw][1], bf, acc[idx][1]);
        }
      }
    }
  }
  float ss[2][4] = {{0,0,0,0},{0,0,0,0}}, sq[2][4] = {{0,0,0,0},{0,0,0,0}};
  for (int idx = 0; idx < 7; ++idx){
    if (idx >= ns) break;
    const int wo = s0 + idx;
    #pragma unroll
    for (int mt = 0; mt < 2; ++mt){
      floatx4 a = acc[idx][mt];
      uint2 st;
      st.x = (unsigned int)f2bu(a.x) | ((unsigned int)f2bu(a.y) << 16);
      st.y = (unsigned int)f2bu(a.z) | ((unsigned int)f2bu(a.w) << 16);
      *(uint2*)(x3 + ((size_t)(ho*55+wo)*1024 + b0 + (L&15))*32 + mt*16 + ((L>>4)&3)*4) = st;
      ss[mt][0] += a.x; ss[mt][1] += a.y; ss[mt][2] += a.z; ss[mt][3] += a.w;
      sq[mt][0] += a.x*a.x; sq[mt][1] += a.y*a.y; sq[mt][2] += a.z*a.z; sq[mt][3] += a.w*a.w;
    }
  }
  #pragma unroll
  for (int mt = 0; mt < 2; ++mt)
    #pragma unroll
    for (int r2 = 0; r2 < 4; ++r2){
      float v1 = ss[mt][r2], v2 = sq[mt][r2];
      for (int d = 1; d < 16; d <<= 1){ v1 += __shfl_xor(v1, d, 64); v2 += __shfl_xor(v2, d, 64); }
      if ((L & 15) == 0){
        int cch = mt*16 + ((L>>4)&3)*4 + r2;
        sred[0][w][cch] = v1;
        sred[1][w][cch] = v2;
      }
    }
  __syncthreads();
  if (t < 64){
    const int cch = t & 31, j = t >> 5;
    float tot = sred[j][0][cch] + sred[j][1][cch] + sred[j][2][cch] + sred[j][3][cch];
    const int bid = (z*36 + blockIdx.y)*64 + blockIdx.x;
    ws[(j ? OFF_P3Q : OFF_P3S) + cch*4608 + bid] = tot;
  }
}

// ============ deconv4 (VALU): x3 (36,55,1024,32) -> o4 (B,36,105) f32 b-major ============
// relation: hi = ho + kh - 1; wd = wo + kw (even), wi = wd/2
__global__ __launch_bounds__(256) void k_dc4(const unsigned short* __restrict__ x3, const float* __restrict__ W4,
                                             float* __restrict__ o4, const float* __restrict__ ws){
  const int t = threadIdx.x;
  const int b = blockIdx.x*64 + (t & 63);
  const int h3 = blockIdx.y*3;
  __shared__ float w4s[480];
  __shared__ float a3s[32], c3s[32];
  if (t < 32){ a3s[t] = ws[OFF_A3+t]; c3s[t] = ws[OFF_C3+t]; }
  for (int i = t; i < 480; i += 256) w4s[i] = W4[i];
  __syncthreads();
  for (int gg = t >> 6; gg < 81; gg += 4){
    const int hl = gg/27, g = gg - hl*27;
    const int ho = h3 + hl;
    float out[4] = {0.f, 0.f, 0.f, 0.f};
    for (int r = 0; r < 3; ++r){
      const int hi = ho - 1 + r;
      if (hi < 0 || hi >= 36) continue;
      for (int dwi = 0; dwi < 4; ++dwi){
        const int wi = 2*g + dwi;
        if (wi >= 55) break;
        float fa[32];
        const unsigned short* px = x3 + ((size_t)(hi*55+wi)*1024 + b)*32;
        #pragma unroll
        for (int q = 0; q < 4; ++q){
          uint4 v = *(const uint4*)(px + q*8);
          unsigned int uu[4] = {v.x, v.y, v.z, v.w};
          #pragma unroll
          for (int k2i = 0; k2i < 4; ++k2i){
            int ci = q*8 + k2i*2;
            float x0 = __uint_as_float(uu[k2i] << 16);
            float x1f = __uint_as_float(uu[k2i] & 0xffff0000u);
            fa[ci]   = fmaxf(fmaf(a3s[ci],   x0,  c3s[ci]),   0.f);
            fa[ci+1] = fmaxf(fmaf(a3s[ci+1], x1f, c3s[ci+1]), 0.f);
          }
        }
        #pragma unroll
        for (int s = 0; s < 4; ++s){
          const int kw = 2*dwi - s;
          if (kw < 0 || kw >= 5) continue;
          const float* wr = &w4s[(r*5 + kw)*32];
          float a = 0.f;
          #pragma unroll
          for (int ci = 0; ci < 32; ++ci) a += fa[ci]*wr[ci];
          out[s] += a;
        }
      }
    }
    const int wo0 = 4*g;
    float* op = o4 + (size_t)b*3780 + ho*105 + wo0;
    #pragma unroll
    for (int s = 0; s < 4; ++s)
      if (wo0 + s < 105) op[s] = out[s];
  }
}

// ============ node softmax / outputs ============
__global__ __launch_bounds__(256) void k_node(const float* __restrict__ o4, float* __restrict__ dout,
                                              float* __restrict__ ws){
  const int t = threadIdx.x;
  const int tg = blockIdx.x*256 + t;
  __shared__ float red[256];
  float lp = 0.f;
  {
    int b = tg / 30, n = tg - b*30;
    const float* p = o4 + (size_t)b*3780 + n*126;
    float l[6]; float mx = -1e30f;
    #pragma unroll
    for (int j = 0; j < 6; ++j){ l[j] = p[j]; mx = fmaxf(mx, l[j]); }
    float e[6]; float s = 0.f;
    #pragma unroll
    for (int j = 0; j < 6; ++j){ e[j] = expf(l[j] - mx); s += e[j]; }
    float inv = 1.f / s;
    int am = 0; float best = e[0];
    #pragma unroll
    for (int j = 1; j < 6; ++j){ if (e[j] > best){ best = e[j]; am = j; } }
    #pragma unroll
    for (int j = 0; j < 5; ++j) dout[OUT0 + (size_t)tg*5 + j] = e[j+1]*inv;
    dout[OUT3 + tg] = 1.f - e[0]*inv;
    #pragma unroll
    for (int j = 0; j < 5; ++j) dout[OUT6 + (size_t)tg*5 + j] = (am == j+1) ? 1.f : 0.f;
    dout[OUT8 + tg] = (am != 0) ? 1.f : 0.f;
    dout[OUT5 + tg] = (float)b;
    lp = logf(best*inv + 1e-7f);
  }
  red[t] = lp; __syncthreads();
  for (int off = 128; off > 0; off >>= 1){ if (t < off) red[t] += red[t+off]; __syncthreads(); }
  if (t == 0) atomicAdd(&ws[OFF_LP], red[0]);
}

// ============ edge softmax / outputs ============
__global__ __launch_bounds__(256) void k_edge(const float* __restrict__ o4, float* __restrict__ dout,
                                              float* __restrict__ ws){
  const int t = threadIdx.x;
  const int tg = blockIdx.x*256 + t;
  __shared__ float red[256];
  float lp = 0.f;
  {
    int b = tg / 435, k = tg - b*435;
    int i = 0, rem = k;
    while (rem >= 29 - i){ rem -= 29 - i; ++i; }
    int j = i + 1 + rem;
    const float* p = o4 + (size_t)b*3780 + i*126 + 6 + j*4;
    float l0 = p[0], l1 = p[1], l2 = p[2], l3 = p[3];
    float mx = fmaxf(fmaxf(l0, l1), fmaxf(l2, l3));
    float e0 = expf(l0-mx), e1 = expf(l1-mx), e2 = expf(l2-mx), e3 = expf(l3-mx);
    float inv = 1.f / (e0 + e1 + e2 + e3);
    float pr0 = e0*inv, pr1 = e1*inv, pr2 = e2*inv, pr3 = e3*inv;
    int am = 0; float best = pr0;
    if (pr1 > best){ best = pr1; am = 1; }
    if (pr2 > best){ best = pr2; am = 2; }
    if (pr3 > best){ best = pr3; am = 3; }
    size_t e1i = (size_t)b*870 + k, e2i = e1i + 435;
    dout[OUT2 + e1i*3 + 0] = pr1; dout[OUT2 + e1i*3 + 1] = pr2; dout[OUT2 + e1i*3 + 2] = pr3;
    dout[OUT2 + e2i*3 + 0] = pr1; dout[OUT2 + e2i*3 + 1] = pr2; dout[OUT2 + e2i*3 + 2] = pr3;
    dout[OUT4 + e1i] = 1.f - pr0;  dout[OUT4 + e2i] = 1.f - pr0;
    float h1 = (am == 1) ? 1.f : 0.f, h2 = (am == 2) ? 1.f : 0.f, h3 = (am == 3) ? 1.f : 0.f;
    dout[OUT7 + e1i*3 + 0] = h1; dout[OUT7 + e1i*3 + 1] = h2; dout[OUT7 + e1i*3 + 2] = h3;
    dout[OUT7 + e2i*3 + 0] = h1; dout[OUT7 + e2i*3 + 1] = h2; dout[OUT7 + e2i*3 + 2] = h3;
    dout[OUT9 + e1i] = (am != 0) ? 1.f : 0.f;  dout[OUT9 + e2i] = (am != 0) ? 1.f : 0.f;
    if (b == 0){
      dout[OUT1 + k]        = (float)i;
      dout[OUT1 + 435 + k]  = (float)j;
      dout[OUT1 + 870 + k]  = (float)j;
      dout[OUT1 + 1305 + k] = (float)i;
    }
    lp = logf(best + 1e-7f);
  }
  red[t] = lp; __syncthreads();
  for (int off = 128; off > 0; off >>= 1){ if (t < off) red[t] += red[t+off]; __syncthreads(); }
  if (t == 0) atomicAdd(&ws[OFF_LP], red[0]);
}

__global__ void k_lp_copy(float* __restrict__ dout, const float* __restrict__ ws){
  if (threadIdx.x == 0 && blockIdx.x == 0) dout[OUT10] = ws[OFF_LP];
}

extern "C" void kernel_launch(void* const* d_in, const int* in_sizes, int n_in,
                              void* d_out, int out_size, void* d_ws, size_t ws_size,
                              hipStream_t stream) {
  const float* Z  = (const float*)d_in[0];
  const float* W1 = (const float*)d_in[1];
  const float* W2 = (const float*)d_in[2];
  const float* W3 = (const float*)d_in[3];
  const float* W4 = (const float*)d_in[4];
  const float* g1 = (const float*)d_in[5];
  const float* b1 = (const float*)d_in[6];
  const float* g2 = (const float*)d_in[7];
  const float* b2 = (const float*)d_in[8];
  const float* g3 = (const float*)d_in[9];
  const float* b3 = (const float*)d_in[10];

  float* ws  = (float*)d_ws;
  char*  wsb = (char*)d_ws;
  unsigned short* fw2 = (unsigned short*)(wsb + FW2_BYTE);
  unsigned short* fw3 = (unsigned short*)(wsb + FW3_BYTE);
  bf16*           x1  = (bf16*)(wsb + X1_BYTE);
  bf16*           x3b = (bf16*)(wsb + X3_BYTE);
  unsigned short* x1u = (unsigned short*)(wsb + X1_BYTE);
  unsigned short* x2u = (unsigned short*)(wsb + X2_BYTE);
  unsigned short* x3u = (unsigned short*)(wsb + X3_BYTE);
  float*          o4  = (float*)(wsb + O4_BYTE);
  float* dout = (float*)d_out;
  (void)x3b; (void)in_sizes; (void)n_in; (void)out_size; (void)ws_size;

  k_prep<<<dim3(9), dim3(256), 0, stream>>>(W2, W3, fw2, fw3);
  k_dc1<<<dim3(1024), dim3(256), 0, stream>>>(Z, W1, x1, ws);
  k_fin<<<dim3(64), dim3(256), 0, stream>>>(ws, g1, b1, OFF_P1S, OFF_P1Q, 1024,
                                            1.f/243712.f, OFF_A1, OFF_C1, 0);
  k2<<<dim3(64, 36), dim3(256), 0, stream>>>(x1u, fw2, x2u, ws);
  k_fin<<<dim3(32), dim3(256), 0, stream>>>(ws, g2, b2, OFF_P2S, OFF_P2Q, 2304,
                                            1.f/995328.f, OFF_A2, OFF_C2, 0);
  k3<<<dim3(64, 36, 2), dim3(256), 0, stream>>>(x2u, fw3, x3u, ws);
  k_fin<<<dim3(32), dim3(256), 0, stream>>>(ws, g3, b3, OFF_P3S, OFF_P3Q, 4608,
                                            1.f/2027520.f, OFF_A3, OFF_C3, 1);
  k_dc4<<<dim3(16, 12), dim3(256), 0, stream>>>(x3u, W4, o4, ws);
  k_node<<<dim3(120), dim3(256), 0, stream>>>(o4, dout, ws);
  k_edge<<<dim3(1740), dim3(256), 0, stream>>>(o4, dout, ws);
  k_lp_copy<<<dim3(1), dim3(64), 0, stream>>>(dout, ws);
}